// Round 1
// baseline (545.089 us; speedup 1.0000x reference)
//
#include <hip/hip_runtime.h>
#include <math.h>

#define NB 32          // MAX_NODES
#define BATCH 16384
#define MPB 8          // matrices per block
#define TPB (MPB * 32) // 256 threads, 4 waves

// ws layout (16 B, zeroed by hipMemsetAsync): [0]=bce_sum [1]=mask_sum [2]=phys_sum [3]=unused

__device__ __forceinline__ float groupReduceSum(float v) {
    // sum within each 32-lane half of the wave (xor masks <=16 stay in-half)
    v += __shfl_xor(v, 1, 64);
    v += __shfl_xor(v, 2, 64);
    v += __shfl_xor(v, 4, 64);
    v += __shfl_xor(v, 8, 64);
    v += __shfl_xor(v, 16, 64);
    return v;
}

// 8 matrices per 256-thread block (each 32-lane group owns one matrix).
// ZERO LDS, zero barriers: all cross-lane traffic via shfl (wave-synchronous).
// Householder k-loop is ROLLED (not unrolled) so the body fits the 32 KB I$;
// all register arrays are indexed only by compile-time constants (no scratch).
__global__ __launch_bounds__(TPB)
void lap_main(const float* __restrict__ predA, const float* __restrict__ targA,
              const float* __restrict__ nmask, float* __restrict__ out,
              float* __restrict__ ws)
{
    const int t    = threadIdx.x;           // 0..255
    const int j    = t & 31;                // row index within matrix
    const int mm   = t >> 5;                // matrix within block (0..7)
    const int half = mm & 1;                // 32-lane half within the wave
    const int b    = blockIdx.x * MPB + mm; // batch index
    const size_t base = (size_t)b * (NB * NB);

    // ---- phase 1: per-lane row loads, BCE partials, pred row -> a[] ----
    const float  mr  = nmask[(size_t)blockIdx.x * (MPB * NB) + t];
    const float4* pr4 = (const float4*)(predA + base + (size_t)j * NB);
    const float4* tr4 = (const float4*)(targA + base + (size_t)j * NB);
    const float4* nm4 = (const float4*)(nmask + (size_t)b * NB);

    float a[NB];
    float accB = 0.f, accM = 0.f;
    #pragma unroll
    for (int q = 0; q < 8; ++q) {
        const float4 p  = pr4[q];
        const float4 tg = tr4[q];
        const float4 mc = nm4[q];
        const float bx = -(tg.x * __logf(p.x) + (1.f - tg.x) * __logf(1.f - p.x));
        const float by = -(tg.y * __logf(p.y) + (1.f - tg.y) * __logf(1.f - p.y));
        const float bz = -(tg.z * __logf(p.z) + (1.f - tg.z) * __logf(1.f - p.z));
        const float bw = -(tg.w * __logf(p.w) + (1.f - tg.w) * __logf(1.f - p.w));
        accB += mr * (mc.x * bx + mc.y * by + mc.z * bz + mc.w * bw);
        accM += mr * (mc.x + mc.y + mc.z + mc.w);
        a[4*q+0] = p.x; a[4*q+1] = p.y; a[4*q+2] = p.z; a[4*q+3] = p.w;
    }
    accB = groupReduceSum(accB); accB += __shfl_xor(accB, 32, 64);
    accM = groupReduceSum(accM); accM += __shfl_xor(accM, 32, 64);
    if ((t & 63) == 0) { atomicAdd(ws + 0, accB); atomicAdd(ws + 1, accM); }

    // ---- phase 2: M = (L+L^T)/2 in place; col coalesced from global ----
    float dsum = 0.f, pdiag = 0.f;
    #pragma unroll
    for (int i = 0; i < NB; ++i) {
        dsum += a[i];
        pdiag = (i == j) ? a[i] : pdiag;
    }
    const float jitter = 1e-5f + (9e-5f / 31.f) * (float)j;
    const float dval = dsum + jitter - pdiag;
    #pragma unroll
    for (int i = 0; i < NB; ++i) {
        const float cv = predA[base + (size_t)i * NB + j];  // coalesced across lanes
        const float s  = -0.5f * (a[i] + cv);
        a[i] = (i == j) ? dval : s;
    }

    // ---- phase 3: Householder tridiagonalization, ROLLED k-loop ----
    // colk carries column k (lane i holds element i); only lanes j>k consume it,
    // and those lanes always took the update path, so stale values on frozen
    // lanes are harmless. All captures (dcap/ecap/next colk) are done inside
    // the constant-index i-loop to avoid runtime register-array indexing.
    float colk = a[0];
    float dcap = 0.f, ecap = 0.f;
    for (int k = 0; k < NB - 2; ++k) {
        const float sg = groupReduceSum((j > k) ? colk * colk : 0.f);
        const float x1 = __shfl(colk, k + 1, 32);
        const float al = (x1 >= 0.f) ? -sqrtf(sg) : sqrtf(sg);
        const float denom = sg - al * x1;
        const float beta  = (denom > 1e-30f) ? __builtin_amdgcn_rcpf(denom) : 0.f;
        const float vj    = (j > k) ? (colk - ((j == k + 1) ? al : 0.f)) : 0.f;

        float xv[NB];   // v_i broadcast to every lane; 0 for i<=k
        #pragma unroll
        for (int i = 0; i < NB; ++i) {
            float cb = __shfl(colk, i, 32);
            cb = (i == k + 1) ? (x1 - al) : cb;
            xv[i] = (i > k) ? cb : 0.f;
        }

        // dot = a_row . v  (8-accumulator pairwise tree; xv[i]=0 masks i<=k)
        float acc[8];
        #pragma unroll
        for (int u = 0; u < 8; ++u) acc[u] = 0.f;
        #pragma unroll
        for (int i = 0; i < NB; ++i) acc[i & 7] += a[i] * xv[i];
        const float dot = ((acc[0] + acc[4]) + (acc[2] + acc[6]))
                        + ((acc[1] + acc[5]) + (acc[3] + acc[7]));

        const float pj = beta * dot;                  // p_j = beta * (A v)_j
        const float K  = groupReduceSum(vj * pj);     // v.p  (vj=0 for j<=k)
        const float c  = 0.5f * beta * K;
        const float s2 = pj - 2.f * c * vj;           // = w_j - c*v_j

        const bool rowlive = (j >= k);
        float ncol = colk;
        #pragma unroll
        for (int i = 0; i < NB; ++i) {
            const float pvi = __shfl(pj, i, 32);      // w_i broadcast
            const float av0 = a[i];
            const float upd = av0 - (vj * pvi + s2 * xv[i]); // -= v_j*w_i + w_j*v_i
            const float av  = (rowlive && (i >= k)) ? upd : av0;
            a[i] = av;
            dcap = ((i == k) && (j == k))     ? av : dcap;  // d_k final after step k
            ecap = ((i == k) && (j == k + 1)) ? av : ecap;  // e_k = A[k+1][k]
            ncol = (i == k + 1) ? av : ncol;                // column k+1 for next step
        }
        colk = ncol;
    }
    if (j == NB - 2) dcap = a[NB - 2];
    if (j == NB - 1) { dcap = a[NB - 1]; ecap = a[NB - 2]; }

    // ---- gather d/e to all lanes via shuffles (no LDS) ----
    float d[NB], e[NB];
    #pragma unroll
    for (int i = 0; i < NB; ++i) d[i] = __shfl(dcap, i, 32);
    #pragma unroll
    for (int i = 0; i < NB - 1; ++i) e[i] = __shfl(ecap, i + 1, 32);
    e[NB - 1] = 0.f;

    // ---- phase 4: Sturm multisection (32 sigmas/round, 3 rounds), rcp-based ----
    float e2[NB];
    #pragma unroll
    for (int i = 0; i < NB; ++i) e2[i] = e[i] * e[i];
    float lo = 1e30f, hi = -1e30f;
    #pragma unroll
    for (int i = 0; i < NB; ++i) {
        const float rr = ((i > 0) ? fabsf(e[i - 1]) : 0.f) + ((i < NB - 1) ? fabsf(e[i]) : 0.f);
        lo = fminf(lo, d[i] - rr);
        hi = fmaxf(hi, d[i] + rr);
    }
    for (int round = 0; round < 3; ++round) {
        const float step = (hi - lo) * (1.f / 33.f);
        const float sig = lo + step * (float)(j + 1);
        float q = d[0] - sig;
        int cnt = (q < 0.f);
        #pragma unroll
        for (int i = 1; i < NB; ++i) {
            if (fabsf(q) < 1e-20f) q = (q < 0.f) ? -1e-20f : 1e-20f;
            q = (d[i] - sig) - e2[i - 1] * __builtin_amdgcn_rcpf(q);
            cnt += (q < 0.f);
        }
        const unsigned long long bal = __ballot(cnt >= 2);
        const unsigned int bits = (unsigned int)(bal >> (half * 32));
        const int jstar = (bits == 0u) ? 32 : __builtin_ctz(bits);
        const float nlo = lo + step * (float)jstar;
        const float nhi = lo + step * (float)(jstar + 1);
        lo = nlo; hi = nhi;
    }
    const float lam2 = 0.5f * (lo + hi);

    if (j == 0) out[2 + b] = lam2;
    const float ph = fmaxf(0.1f - lam2, 0.f);
    const float ph0 = __shfl(ph, 0, 64);
    const float ph1 = __shfl(ph, 32, 64);
    if ((t & 63) == 0) atomicAdd(ws + 2, ph0 + ph1);   // one add per wave (2 matrices)
}

__global__ __launch_bounds__(64)
void lap_final(float* __restrict__ out, const float* __restrict__ ws) {
    if (threadIdx.x == 0) {
        out[0] = ws[0] / fmaxf(ws[1], 1.f);
        out[1] = ws[2] * (1.f / (float)BATCH);
    }
}

extern "C" void kernel_launch(void* const* d_in, const int* in_sizes, int n_in,
                              void* d_out, int out_size, void* d_ws, size_t ws_size,
                              hipStream_t stream) {
    const float* pred = (const float*)d_in[0];
    const float* targ = (const float*)d_in[1];
    const float* nm   = (const float*)d_in[2];
    float* out = (float*)d_out;
    float* ws  = (float*)d_ws;

    (void)hipMemsetAsync(d_ws, 0, 16, stream);
    hipLaunchKernelGGL(lap_main, dim3(BATCH / MPB), dim3(TPB), 0, stream,
                       pred, targ, nm, out, ws);
    hipLaunchKernelGGL(lap_final, dim3(1), dim3(64), 0, stream, out, ws);
}

// Round 3
// 498.767 us; speedup vs baseline: 1.0929x; 1.0929x over previous
//
#include <hip/hip_runtime.h>
#include <math.h>

#define NB 32          // MAX_NODES
#define BATCH 16384
#define MPB 8          // matrices per block
#define TPB (MPB * 32) // 256 threads, 4 waves

// ws layout (16 B, zeroed by hipMemsetAsync): [0]=bce_sum [1]=mask_sum [2]=phys_sum [3]=unused

__device__ __forceinline__ float groupReduceSum(float v) {
    // sum within each 32-lane group (xor masks <=16 stay in-group)
    v += __shfl_xor(v, 1, 64);
    v += __shfl_xor(v, 2, 64);
    v += __shfl_xor(v, 4, 64);
    v += __shfl_xor(v, 8, 64);
    v += __shfl_xor(v, 16, 64);
    return v;
}

// 8 matrices per 256-thread block (each 32-lane group owns one matrix).
// ZERO LDS, zero barriers: all cross-lane traffic via shfl (register-only,
// wave-synchronous -> no ordering hazards). Phase-3 algebra is line-by-line
// the round-0/1 verified version; the only structural deltas are:
//   (1) wave-uniform chunk skips (4q+3>=k) -- skipped terms were exactly 0
//   (2) HARD row guard if(j>=k) around the update -> frozen rows provably
//       never touched -> d/e extracted once at the end from registers
// (Round-2 lesson: do NOT replace the hard guard with "update is
//  arithmetically zero" + un-barriered LDS broadcasts; it broke silently.)
__global__ __launch_bounds__(TPB, 4)
void lap_main(const float* __restrict__ predA, const float* __restrict__ targA,
              const float* __restrict__ nmask, float* __restrict__ out,
              float* __restrict__ ws)
{
    const int t    = threadIdx.x;           // 0..255
    const int j    = t & 31;                // row index within matrix
    const int mm   = t >> 5;                // matrix within block (0..7)
    const int half = mm & 1;                // 32-lane half within the wave
    const int b    = blockIdx.x * MPB + mm; // batch index
    const size_t base = (size_t)b * (NB * NB);

    // ---- phase 1: per-lane row loads, BCE partials, pred row -> a[] ----
    const float  mr  = nmask[(size_t)blockIdx.x * (MPB * NB) + t];
    const float4* pr4 = (const float4*)(predA + base + (size_t)j * NB);
    const float4* tr4 = (const float4*)(targA + base + (size_t)j * NB);
    const float4* nm4 = (const float4*)(nmask + (size_t)b * NB);

    float a[NB];
    float accB = 0.f, accM = 0.f;
    #pragma unroll
    for (int q = 0; q < 8; ++q) {
        const float4 p  = pr4[q];
        const float4 tg = tr4[q];
        const float4 mc = nm4[q];
        const float bx = -(tg.x * __logf(p.x) + (1.f - tg.x) * __logf(1.f - p.x));
        const float by = -(tg.y * __logf(p.y) + (1.f - tg.y) * __logf(1.f - p.y));
        const float bz = -(tg.z * __logf(p.z) + (1.f - tg.z) * __logf(1.f - p.z));
        const float bw = -(tg.w * __logf(p.w) + (1.f - tg.w) * __logf(1.f - p.w));
        accB += mr * (mc.x * bx + mc.y * by + mc.z * bz + mc.w * bw);
        accM += mr * (mc.x + mc.y + mc.z + mc.w);
        a[4*q+0] = p.x; a[4*q+1] = p.y; a[4*q+2] = p.z; a[4*q+3] = p.w;
    }
    accB = groupReduceSum(accB); accB += __shfl_xor(accB, 32, 64);
    accM = groupReduceSum(accM); accM += __shfl_xor(accM, 32, 64);
    if ((t & 63) == 0) { atomicAdd(ws + 0, accB); atomicAdd(ws + 1, accM); }

    // ---- phase 2: M = (L+L^T)/2 in place; col coalesced from global ----
    float dsum = 0.f, pdiag = 0.f;
    #pragma unroll
    for (int i = 0; i < NB; ++i) {
        dsum += a[i];
        pdiag = (i == j) ? a[i] : pdiag;
    }
    const float jitter = 1e-5f + (9e-5f / 31.f) * (float)j;
    const float dval = dsum + jitter - pdiag;
    #pragma unroll
    for (int i = 0; i < NB; ++i) {
        const float cv = predA[base + (size_t)i * NB + j];  // coalesced across lanes
        const float s  = -0.5f * (a[i] + cv);
        a[i] = (i == j) ? dval : s;
    }

    // ---- phase 3: Householder tridiagonalization, rolled, shfl broadcasts ----
    float xv[NB];
    #pragma unroll
    for (int i = 0; i < NB; ++i) xv[i] = 0.f;
    float colk = a[0];                      // lane j holds A[j][k] for current k
    for (int k = 0; k < NB - 2; ++k) {
        const float sg = groupReduceSum((j > k) ? colk * colk : 0.f);
        const float x1 = __shfl(colk, k + 1, 32);
        const float al = (x1 >= 0.f) ? -sqrtf(sg) : sqrtf(sg);
        const float denom = sg - al * x1;
        const float beta  = (denom > 1e-30f) ? __builtin_amdgcn_rcpf(denom) : 0.f;
        const float vj = (j > k) ? (colk - ((j == k + 1) ? al : 0.f)) : 0.f;

        // broadcast v (all lanes active) + dot = a_row . v, skipping dead chunks
        // (k is wave-uniform -> s_cbranch, no divergence; skipped terms were 0)
        float ac0 = 0.f, ac1 = 0.f, ac2 = 0.f, ac3 = 0.f;
        #pragma unroll
        for (int q = 0; q < 8; ++q) {
            if (4*q + 3 >= k) {
                #pragma unroll
                for (int u = 0; u < 4; ++u) {
                    const int i = 4*q + u;
                    float cb = __shfl(colk, i, 32);
                    cb = (i == k + 1) ? (x1 - al) : cb;   // uniform cond
                    xv[i] = (i > k) ? cb : 0.f;           // uniform cond
                }
                ac0 += a[4*q+0] * xv[4*q+0];
                ac1 += a[4*q+1] * xv[4*q+1];
                ac2 += a[4*q+2] * xv[4*q+2];
                ac3 += a[4*q+3] * xv[4*q+3];
            }
        }
        const float dot = (ac0 + ac1) + (ac2 + ac3);
        const float pj  = beta * dot;
        const float pjm = (j >= k) ? pj : 0.f;     // frozen lanes contribute 0
        const float K   = groupReduceSum(vj * pjm); // all lanes active
        const float c   = 0.5f * beta * K;
        const float s2  = pjm - 2.f * c * vj;
        const float nvj = -vj, ns2 = -s2;

        // rank-2 update under HARD row guard: frozen rows provably untouched.
        // shfl sources (lanes i>=k) are inside the guard -> active.
        float ncol = colk;
        if (j >= k) {
            #pragma unroll
            for (int q = 0; q < 8; ++q) {
                if (4*q + 3 >= k) {
                    #pragma unroll
                    for (int u = 0; u < 4; ++u) {
                        const int i = 4*q + u;
                        if (i >= k) {                       // uniform cond
                            const float pv = __shfl(pj, i, 32);
                            float av = a[i];
                            av = fmaf(nvj, pv, av);
                            av = fmaf(ns2, xv[i], av);
                            a[i] = av;
                            ncol = (i == k + 1) ? av : ncol; // carry col k+1
                        }
                    }
                }
            }
        }
        colk = ncol;
    }

    // ---- extract d/e + Gershgorin bounds; rows kept final values (guard) ----
    float d[NB], e2[NB];
    float lo = 1e30f, hi = -1e30f;
    float eprev = 0.f;
    #pragma unroll
    for (int i = 0; i < NB; ++i) {
        d[i] = __shfl(a[i], i, 32);                          // A[i][i]
        const float ei  = (i < NB - 1) ? __shfl(a[i], i + 1, 32) : 0.f; // A[i+1][i]
        const float aei = fabsf(ei);
        lo = fminf(lo, d[i] - (eprev + aei));
        hi = fmaxf(hi, d[i] + (eprev + aei));
        e2[i] = ei * ei;
        eprev = aei;
    }

    // ---- phase 4: Sturm multisection (32 sigmas/round, 3 rounds), rcp-based ----
    for (int round = 0; round < 3; ++round) {
        const float step = (hi - lo) * (1.f / 33.f);
        const float sig = lo + step * (float)(j + 1);
        float q = d[0] - sig;
        int cnt = (q < 0.f);
        #pragma unroll
        for (int i = 1; i < NB; ++i) {
            if (fabsf(q) < 1e-20f) q = (q < 0.f) ? -1e-20f : 1e-20f;
            q = (d[i] - sig) - e2[i - 1] * __builtin_amdgcn_rcpf(q);
            cnt += (q < 0.f);
        }
        const unsigned long long bal = __ballot(cnt >= 2);
        const unsigned int bits = (unsigned int)(bal >> (half * 32));
        const int jstar = (bits == 0u) ? 32 : __builtin_ctz(bits);
        const float nlo = lo + step * (float)jstar;
        const float nhi = lo + step * (float)(jstar + 1);
        lo = nlo; hi = nhi;
    }
    const float lam2 = 0.5f * (lo + hi);

    if (j == 0) out[2 + b] = lam2;
    const float ph = fmaxf(0.1f - lam2, 0.f);
    const float ph0 = __shfl(ph, 0, 64);
    const float ph1 = __shfl(ph, 32, 64);
    if ((t & 63) == 0) atomicAdd(ws + 2, ph0 + ph1);   // one add per wave (2 matrices)
}

__global__ __launch_bounds__(64)
void lap_final(float* __restrict__ out, const float* __restrict__ ws) {
    if (threadIdx.x == 0) {
        out[0] = ws[0] / fmaxf(ws[1], 1.f);
        out[1] = ws[2] * (1.f / (float)BATCH);
    }
}

extern "C" void kernel_launch(void* const* d_in, const int* in_sizes, int n_in,
                              void* d_out, int out_size, void* d_ws, size_t ws_size,
                              hipStream_t stream) {
    const float* pred = (const float*)d_in[0];
    const float* targ = (const float*)d_in[1];
    const float* nm   = (const float*)d_in[2];
    float* out = (float*)d_out;
    float* ws  = (float*)d_ws;

    (void)hipMemsetAsync(d_ws, 0, 16, stream);
    hipLaunchKernelGGL(lap_main, dim3(BATCH / MPB), dim3(TPB), 0, stream,
                       pred, targ, nm, out, ws);
    hipLaunchKernelGGL(lap_final, dim3(1), dim3(64), 0, stream, out, ws);
}